// Round 7
// baseline (478.888 us; speedup 1.0000x reference)
//
#include <hip/hip_runtime.h>
#include <math.h>

namespace {

constexpr int BB = 2;
constexpr int HH = 160;
constexpr int WW = 160;
constexpr int DD = 160;
constexpr int NV = BB * HH * WW * DD;   // 8,192,000
constexpr int NV4 = NV / 4;             // 2,048,000 float4 elements
constexpr int RAD = 4;                  // window 9
constexpr float WVOL = 729.0f;          // (729.0 + 1e-5) rounds to 729.0f in f32
constexpr float EPSF = 1e-5f;

constexpr int SW4 = DD / 4;             // 40  float4 stride along w
constexpr int SH4 = WW * DD / 4;        // 6400 float4 stride along h

constexpr int BLK = 256;
constexpr int GRD4 = NV4 / BLK;         // 8000 (exact)

__device__ __forceinline__ float4 f4z() { return make_float4(0.f, 0.f, 0.f, 0.f); }

// out.{x,y,z,w} = 9-sum sliding window over f[0..11], ascending order (matches
// scalar k=-4..+4 tap order → bit-exact vs reference path that scored absmax 0.0)
__device__ __forceinline__ void slide9(const float* f, float4& o) {
    float s0 = 0.f, s1 = 0.f, s2 = 0.f, s3 = 0.f;
#pragma unroll
    for (int m = 0; m < 9; ++m) {
        s0 += f[m];
        s1 += f[m + 1];
        s2 += f[m + 2];
        s3 += f[m + 3];
    }
    o.x = s0; o.y = s1; o.z = s2; o.w = s3;
}

__device__ __forceinline__ void acc4(float4& s, const float4 v, bool ok) {
    // adds v (or exact 0.0f) — preserves ascending-tap accumulation order
    s.x += ok ? v.x : 0.f;
    s.y += ok ? v.y : 0.f;
    s.z += ok ? v.z : 0.f;
    s.w += ok ? v.w : 0.f;
}

// ---------------- K1: 9-tap box along d (vectorized), two fields ----------------
__global__ void k1_box_d4(const float4* __restrict__ t, const float4* __restrict__ p,
                          float4* __restrict__ st, float4* __restrict__ sp) {
    int i = blockIdx.x * BLK + threadIdx.x;
    int d4 = i % SW4;
    bool lo = d4 > 0, hi = d4 < SW4 - 1;
    float4 z = f4z();
    float4 a0 = lo ? t[i - 1] : z, a1 = t[i], a2 = hi ? t[i + 1] : z;
    float4 b0 = lo ? p[i - 1] : z, b1 = p[i], b2 = hi ? p[i + 1] : z;
    float fa[12] = {a0.x, a0.y, a0.z, a0.w, a1.x, a1.y, a1.z, a1.w, a2.x, a2.y, a2.z, a2.w};
    float fb[12] = {b0.x, b0.y, b0.z, b0.w, b1.x, b1.y, b1.z, b1.w, b2.x, b2.y, b2.z, b2.w};
    float4 oa, ob;
    slide9(fa, oa);
    slide9(fb, ob);
    st[i] = oa; sp[i] = ob;
}

// ---------------- K2: 9-tap box along w (vectorized), two fields ----------------
__global__ void k2_box_w4(const float4* __restrict__ st, const float4* __restrict__ sp,
                          float4* __restrict__ st2, float4* __restrict__ sp2) {
    int i = blockIdx.x * BLK + threadIdx.x;
    int w = (i / SW4) % WW;
    float4 sa = f4z(), sb = f4z();
#pragma unroll
    for (int k = -RAD; k <= RAD; ++k) {
        bool ok = (unsigned)(w + k) < (unsigned)WW;
        int j = i + (ok ? k : 0) * SW4;
        acc4(sa, st[j], ok);
        acc4(sb, sp[j], ok);
    }
    st2[i] = sa; sp2[i] = sb;
}

// ---------------- K3: 9-tap box along h (vectorized) + /729 -> means ----------------
__global__ void k3_box_h_mean4(const float4* __restrict__ st2, const float4* __restrict__ sp2,
                               float4* __restrict__ mt, float4* __restrict__ mp) {
    int i = blockIdx.x * BLK + threadIdx.x;
    int h = (i / SH4) % HH;
    float4 sa = f4z(), sb = f4z();
#pragma unroll
    for (int k = -RAD; k <= RAD; ++k) {
        bool ok = (unsigned)(h + k) < (unsigned)HH;
        int j = i + (ok ? k : 0) * SH4;
        acc4(sa, st2[j], ok);
        acc4(sb, sp2[j], ok);
    }
    sa.x /= WVOL; sa.y /= WVOL; sa.z /= WVOL; sa.w /= WVOL;
    sb.x /= WVOL; sb.y /= WVOL; sb.z /= WVOL; sb.w /= WVOL;
    mt[i] = sa; mp[i] = sb;
}

// ---------------- K4: q = (td*td, pd*pd, td*pd) on the fly + 9-tap d-box ----------------
__global__ void k4_q_box_d4(const float4* __restrict__ t, const float4* __restrict__ p,
                            const float4* __restrict__ mt, const float4* __restrict__ mp,
                            float4* __restrict__ a1, float4* __restrict__ b1,
                            float4* __restrict__ c1) {
    int i = blockIdx.x * BLK + threadIdx.x;
    int d4 = i % SW4;
    bool lo = d4 > 0, hi = d4 < SW4 - 1;
    float4 z = f4z();
    float4 t0 = lo ? t[i - 1] : z,  t1 = t[i],  t2 = hi ? t[i + 1] : z;
    float4 p0 = lo ? p[i - 1] : z,  p1 = p[i],  p2 = hi ? p[i + 1] : z;
    float4 u0 = lo ? mt[i - 1] : z, u1 = mt[i], u2 = hi ? mt[i + 1] : z;
    float4 v0 = lo ? mp[i - 1] : z, v1 = mp[i], v2 = hi ? mp[i + 1] : z;
    float ft[12] = {t0.x, t0.y, t0.z, t0.w, t1.x, t1.y, t1.z, t1.w, t2.x, t2.y, t2.z, t2.w};
    float fp[12] = {p0.x, p0.y, p0.z, p0.w, p1.x, p1.y, p1.z, p1.w, p2.x, p2.y, p2.z, p2.w};
    float fu[12] = {u0.x, u0.y, u0.z, u0.w, u1.x, u1.y, u1.z, u1.w, u2.x, u2.y, u2.z, u2.w};
    float fv[12] = {v0.x, v0.y, v0.z, v0.w, v1.x, v1.y, v1.z, v1.w, v2.x, v2.y, v2.z, v2.w};
    float qa[12], qb[12], qc[12];
#pragma unroll
    for (int m = 0; m < 12; ++m) {
        float td = ft[m] - fu[m];   // out-of-range: 0 - 0 = 0, exact
        float pd = fp[m] - fv[m];
        qa[m] = td * td;
        qb[m] = pd * pd;
        qc[m] = td * pd;
    }
    float4 oa, ob, oc;
    slide9(qa, oa);
    slide9(qb, ob);
    slide9(qc, oc);
    a1[i] = oa; b1[i] = ob; c1[i] = oc;
}

// ---------------- K5: 9-tap box along w (vectorized), three fields ----------------
__global__ void k5_box_w34(const float4* __restrict__ a1, const float4* __restrict__ b1,
                           const float4* __restrict__ c1,
                           float4* __restrict__ a2, float4* __restrict__ b2,
                           float4* __restrict__ c2) {
    int i = blockIdx.x * BLK + threadIdx.x;
    int w = (i / SW4) % WW;
    float4 sa = f4z(), sb = f4z(), sc = f4z();
#pragma unroll
    for (int k = -RAD; k <= RAD; ++k) {
        bool ok = (unsigned)(w + k) < (unsigned)WW;
        int j = i + (ok ? k : 0) * SW4;
        acc4(sa, a1[j], ok);
        acc4(sb, b1[j], ok);
        acc4(sc, c1[j], ok);
    }
    a2[i] = sa; b2[i] = sb; c2[i] = sc;
}

// ---------------- K6: 9-tap box along h, three fields + cc + block partial ----------------
__global__ void k6_box_h3_cc_partial4(const float4* __restrict__ a2, const float4* __restrict__ b2,
                                      const float4* __restrict__ c2,
                                      double* __restrict__ partials) {
    int i = blockIdx.x * BLK + threadIdx.x;
    int h = (i / SH4) % HH;
    float4 sa = f4z(), sb = f4z(), sc = f4z();
#pragma unroll
    for (int k = -RAD; k <= RAD; ++k) {
        bool ok = (unsigned)(h + k) < (unsigned)HH;
        int j = i + (ok ? k : 0) * SH4;
        acc4(sa, a2[j], ok);
        acc4(sb, b2[j], ok);
        acc4(sc, c2[j], ok);
    }
    float c0 = sc.x / sqrtf((sa.x + EPSF) * (sb.x + EPSF));
    float c1_ = sc.y / sqrtf((sa.y + EPSF) * (sb.y + EPSF));
    float c2_ = sc.z / sqrtf((sa.z + EPSF) * (sb.z + EPSF));
    float c3 = sc.w / sqrtf((sa.w + EPSF) * (sb.w + EPSF));
    double v = (double)c0 + (double)c1_ + (double)c2_ + (double)c3;
    // wave reduce (64 lanes)
#pragma unroll
    for (int off = 32; off > 0; off >>= 1)
        v += __shfl_down(v, off, 64);
    __shared__ double red[4];
    int lane = threadIdx.x & 63;
    int wv = threadIdx.x >> 6;
    if (lane == 0) red[wv] = v;
    __syncthreads();
    if (threadIdx.x == 0)
        partials[blockIdx.x] = red[0] + red[1] + red[2] + red[3];
}

// ---------------- K7: reduce 8000 partials + finalize ----------------
__global__ void k7_reduce(const double* __restrict__ partials, float* __restrict__ out) {
    __shared__ double red[256];
    double s = 0.0;
    for (int i = threadIdx.x; i < GRD4; i += 256)
        s += partials[i];
    red[threadIdx.x] = s;
    __syncthreads();
    for (int ofs = 128; ofs > 0; ofs >>= 1) {
        if (threadIdx.x < ofs) red[threadIdx.x] += red[threadIdx.x + ofs];
        __syncthreads();
    }
    if (threadIdx.x == 0)
        out[0] = -(float)(red[0] / (double)NV);
}

} // anonymous namespace

extern "C" void kernel_launch(void* const* d_in, const int* in_sizes, int n_in,
                              void* d_out, int out_size, void* d_ws, size_t ws_size,
                              hipStream_t stream) {
    const float4* t = (const float4*)d_in[0];
    const float4* p = (const float4*)d_in[1];
    float* out = (float*)d_out;

    char* ws = (char*)d_ws;
    float4* F0 = (float4*)(ws + 256);
    float4* F1 = F0 + NV4;
    float4* F2 = F1 + NV4;
    float4* F3 = F2 + NV4;
    float4* F4 = F3 + NV4;
    float4* F5 = F4 + NV4;

    // K1: d-box of t,p -> F0 (st), F1 (sp)
    k1_box_d4<<<GRD4, BLK, 0, stream>>>(t, p, F0, F1);
    // K2: w-box -> F2 (st2), F3 (sp2)
    k2_box_w4<<<GRD4, BLK, 0, stream>>>(F0, F1, F2, F3);
    // K3: h-box + /729 -> F0 (mt), F1 (mp)   [st/sp dead]
    k3_box_h_mean4<<<GRD4, BLK, 0, stream>>>(F2, F3, F0, F1);
    // K4: q + d-box -> F2 (a1), F3 (b1), F4 (c1)   [st2/sp2 dead]
    k4_q_box_d4<<<GRD4, BLK, 0, stream>>>(t, p, F0, F1, F2, F3, F4);
    // K5: w-box of q -> F0 (a2), F1 (b2), F5 (c2)   [means dead]
    k5_box_w34<<<GRD4, BLK, 0, stream>>>(F2, F3, F4, F0, F1, F5);
    // K6: h-box of q + cc + per-block partials (reuse dead F2)
    double* partials = (double*)F2;
    k6_box_h3_cc_partial4<<<GRD4, BLK, 0, stream>>>(F0, F1, F5, partials);
    // K7: final reduce + negate/mean
    k7_reduce<<<1, 256, 0, stream>>>(partials, out);
}

// Round 10
// 318.830 us; speedup vs baseline: 1.5020x; 1.5020x over previous
//
#include <hip/hip_runtime.h>
#include <math.h>

namespace {

constexpr int BB = 2;
constexpr int HH = 160;
constexpr int WW = 160;
constexpr int DD = 160;
constexpr int NV = BB * HH * WW * DD;   // 8,192,000
constexpr float WVOL = 729.0f;          // (729.0 + 1e-5) rounds to 729.0f in f32
constexpr float EPSF = 1e-5f;

constexpr int SLICE = WW * DD;          // 25600 floats per (b,h) slice

// tiling: block owns 16x16 (w,d) tile, marches h over one of 4 segments
constexpr int Wt = 16, Dt = 16;
constexpr int WH = Wt + 8;              // 24 (w halo)
constexpr int DH = Dt + 8;              // 24 (d halo)
constexpr int Hseg = 40;
constexpr int NWT = WW / Wt;            // 10
constexpr int NDT = DD / Dt;            // 10
constexpr int NHS = HH / Hseg;          // 4
constexpr int NBLK = BB * NHS * NWT * NDT;  // 800

// ---------------- Pass A: fused d+w+h box of t,p -> means (/729) ----------------
__global__ __launch_bounds__(256) void pa_mean(const float* __restrict__ t,
                                               const float* __restrict__ p,
                                               float* __restrict__ mt,
                                               float* __restrict__ mp) {
    __shared__ float sT[WH * DH], sP[WH * DH];   // staged halo slice
    __shared__ float dT[WH * Dt], dP[WH * Dt];   // d-boxed
    int bid = blockIdx.x;
    int dt_ = bid % NDT; int r = bid / NDT;
    int wt_ = r % NWT;   r /= NWT;
    int hs  = r % NHS;   int b = r / NHS;
    int w0 = wt_ * Wt, d0 = dt_ * Dt, h0 = hs * Hseg;
    int tw = threadIdx.x >> 4, td = threadIdx.x & 15;
    const float* tB = t + (size_t)b * HH * SLICE;
    const float* pB = p + (size_t)b * HH * SLICE;
    // 9-deep shift ring of dw-boxed values (compile-time indices only)
    float rT[9], rP[9];
#pragma unroll
    for (int m = 0; m < 9; ++m) { rT[m] = 0.f; rP[m] = 0.f; }

    for (int j = h0 - 4; j < h0 + Hseg + 4; ++j) {
        bool jok = (unsigned)j < (unsigned)HH;
        // stage slice j with zero-fill halo (exact zero-pad semantics)
        for (int li = threadIdx.x; li < WH * DH; li += 256) {
            int lw = li / DH, ld = li - lw * DH;
            int gw = w0 - 4 + lw, gd = d0 - 4 + ld;
            float vt = 0.f, vp = 0.f;
            if (jok && (unsigned)gw < (unsigned)WW && (unsigned)gd < (unsigned)DD) {
                int g = j * SLICE + gw * DD + gd;
                vt = tB[g]; vp = pB[g];
            }
            sT[li] = vt; sP[li] = vp;
        }
        __syncthreads();
        // d-box (ascending d)
        for (int li = threadIdx.x; li < WH * Dt; li += 256) {
            int lw = li >> 4, ld = li & 15;
            const float* r1 = &sT[lw * DH + ld];
            const float* r2 = &sP[lw * DH + ld];
            float s1 = 0.f, s2 = 0.f;
#pragma unroll
            for (int m = 0; m < 9; ++m) { s1 += r1[m]; s2 += r2[m]; }
            dT[li] = s1; dP[li] = s2;
        }
        __syncthreads();
        // w-box (ascending w) + push into ring
        float s1 = 0.f, s2 = 0.f;
#pragma unroll
        for (int m = 0; m < 9; ++m) { s1 += dT[(tw + m) * Dt + td]; s2 += dP[(tw + m) * Dt + td]; }
#pragma unroll
        for (int m = 0; m < 8; ++m) { rT[m] = rT[m + 1]; rP[m] = rP[m + 1]; }
        rT[8] = s1; rP[8] = s2;
        // h-box (ascending h: ring[0]=h-4 ... ring[8]=h+4) + store
        int h = j - 4;
        if (h >= h0) {
            float a = 0.f, c = 0.f;
#pragma unroll
            for (int m = 0; m < 9; ++m) { a += rT[m]; c += rP[m]; }
            int g = (b * HH + h) * SLICE + (w0 + tw) * DD + (d0 + td);
            mt[g] = a / WVOL; mp[g] = c / WVOL;
        }
        __syncthreads();
    }
}

// ---------------- Pass B: q = (td*td,pd*pd,td*pd) + fused d+w+h box + cc + partial ----------------
__global__ __launch_bounds__(256) void pb_cc(const float* __restrict__ t,
                                             const float* __restrict__ p,
                                             const float* __restrict__ mt,
                                             const float* __restrict__ mp,
                                             double* __restrict__ partials) {
    __shared__ float qA[WH * DH], qB[WH * DH], qC[WH * DH];
    __shared__ float dA[WH * Dt], dB[WH * Dt], dC[WH * Dt];
    int bid = blockIdx.x;
    int dt_ = bid % NDT; int r = bid / NDT;
    int wt_ = r % NWT;   r /= NWT;
    int hs  = r % NHS;   int b = r / NHS;
    int w0 = wt_ * Wt, d0 = dt_ * Dt, h0 = hs * Hseg;
    int tw = threadIdx.x >> 4, td = threadIdx.x & 15;
    size_t boff = (size_t)b * HH * SLICE;
    const float* tB = t + boff;
    const float* pB = p + boff;
    const float* uB = mt + boff;
    const float* vB = mp + boff;
    float rA[9], rB[9], rC[9];
#pragma unroll
    for (int m = 0; m < 9; ++m) { rA[m] = 0.f; rB[m] = 0.f; rC[m] = 0.f; }
    double acc = 0.0;

    for (int j = h0 - 4; j < h0 + Hseg + 4; ++j) {
        bool jok = (unsigned)j < (unsigned)HH;
        // stage q on halo'd slice (outside volume: td=pd=0 -> q=0, exact)
        for (int li = threadIdx.x; li < WH * DH; li += 256) {
            int lw = li / DH, ld = li - lw * DH;
            int gw = w0 - 4 + lw, gd = d0 - 4 + ld;
            float av = 0.f, bv = 0.f, cv = 0.f;
            if (jok && (unsigned)gw < (unsigned)WW && (unsigned)gd < (unsigned)DD) {
                int g = j * SLICE + gw * DD + gd;
                float tdv = tB[g] - uB[g];
                float pdv = pB[g] - vB[g];
                av = tdv * tdv; bv = pdv * pdv; cv = tdv * pdv;
            }
            qA[li] = av; qB[li] = bv; qC[li] = cv;
        }
        __syncthreads();
        // d-box (ascending d)
        for (int li = threadIdx.x; li < WH * Dt; li += 256) {
            int lw = li >> 4, ld = li & 15;
            const float* r1 = &qA[lw * DH + ld];
            const float* r2 = &qB[lw * DH + ld];
            const float* r3 = &qC[lw * DH + ld];
            float s1 = 0.f, s2 = 0.f, s3 = 0.f;
#pragma unroll
            for (int m = 0; m < 9; ++m) { s1 += r1[m]; s2 += r2[m]; s3 += r3[m]; }
            dA[li] = s1; dB[li] = s2; dC[li] = s3;
        }
        __syncthreads();
        // w-box (ascending w) + ring push
        float s1 = 0.f, s2 = 0.f, s3 = 0.f;
#pragma unroll
        for (int m = 0; m < 9; ++m) {
            int o = (tw + m) * Dt + td;
            s1 += dA[o]; s2 += dB[o]; s3 += dC[o];
        }
#pragma unroll
        for (int m = 0; m < 8; ++m) { rA[m] = rA[m + 1]; rB[m] = rB[m + 1]; rC[m] = rC[m + 1]; }
        rA[8] = s1; rB[8] = s2; rC[8] = s3;
        // h-box (ascending h) + cc + accumulate
        int h = j - 4;
        if (h >= h0) {
            float sa = 0.f, sb = 0.f, sc = 0.f;
#pragma unroll
            for (int m = 0; m < 9; ++m) { sa += rA[m]; sb += rB[m]; sc += rC[m]; }
            float cc = sc / sqrtf((sa + EPSF) * (sb + EPSF));
            acc += (double)cc;
        }
        __syncthreads();
    }

    // block reduce (wave shuffle, 64 lanes, then LDS)
#pragma unroll
    for (int off = 32; off > 0; off >>= 1)
        acc += __shfl_down(acc, off, 64);
    __shared__ double red[4];
    int lane = threadIdx.x & 63;
    int wv = threadIdx.x >> 6;
    if (lane == 0) red[wv] = acc;
    __syncthreads();
    if (threadIdx.x == 0)
        partials[blockIdx.x] = red[0] + red[1] + red[2] + red[3];
}

// ---------------- K7: reduce 800 partials + finalize ----------------
__global__ void k7_reduce(const double* __restrict__ partials, float* __restrict__ out) {
    __shared__ double red[256];
    double s = 0.0;
    for (int i = threadIdx.x; i < NBLK; i += 256)
        s += partials[i];
    red[threadIdx.x] = s;
    __syncthreads();
    for (int ofs = 128; ofs > 0; ofs >>= 1) {
        if (threadIdx.x < ofs) red[threadIdx.x] += red[threadIdx.x + ofs];
        __syncthreads();
    }
    if (threadIdx.x == 0)
        out[0] = -(float)(red[0] / (double)NV);
}

} // anonymous namespace

extern "C" void kernel_launch(void* const* d_in, const int* in_sizes, int n_in,
                              void* d_out, int out_size, void* d_ws, size_t ws_size,
                              hipStream_t stream) {
    const float* t = (const float*)d_in[0];
    const float* p = (const float*)d_in[1];
    float* out = (float*)d_out;

    char* ws = (char*)d_ws;
    double* partials = (double*)ws;                       // 800 doubles
    float* mt = (float*)(ws + 16384);                     // NV floats
    float* mp = mt + NV;                                  // NV floats

    // Pass A: means
    pa_mean<<<NBLK, 256, 0, stream>>>(t, p, mt, mp);
    // Pass B: cc partials
    pb_cc<<<NBLK, 256, 0, stream>>>(t, p, mt, mp, partials);
    // Final reduce
    k7_reduce<<<1, 256, 0, stream>>>(partials, out);
}

// Round 11
// 289.952 us; speedup vs baseline: 1.6516x; 1.0996x over previous
//
#include <hip/hip_runtime.h>
#include <math.h>

namespace {

constexpr int BB = 2;
constexpr int HH = 160;
constexpr int WW = 160;
constexpr int DD = 160;
constexpr int NV = BB * HH * WW * DD;   // 8,192,000
constexpr float WVOL = 729.0f;          // (729.0 + 1e-5) rounds to 729.0f in f32
constexpr float EPSF = 1e-5f;

constexpr int SLICE4 = WW * DD / 4;     // 6400 quads per (b,h) slice
constexpr int FIELD4 = HH * SLICE4;     // 1,024,000 quads per b

// tiling: block owns 32 w x 32 d (8 quads), marches h over one of 8 segments
constexpr int Wt = 32, Qt = 8;          // output: 32 w x 8 quads = 256 threads
constexpr int WHs = Wt + 8;             // 40 staged w rows
constexpr int QHs = Qt + 2;             // 10 staged quads (d-halo = 1 quad each side)
constexpr int SSTR = 11;                // staged row stride (pad 10->11, odd => conflict-free b128)
constexpr int DSTR = 9;                 // d-boxed row stride (pad 8->9)
constexpr int Hseg = 20;
constexpr int NHS = HH / Hseg;          // 8
constexpr int NWT = WW / Wt;            // 5
constexpr int NQT = DD / (4 * Qt);      // 5
constexpr int NTILE = NWT * NQT;        // 25
constexpr int NSEG = BB * NHS;          // 16
constexpr int NBLK = NTILE * NSEG;      // 400

__device__ __forceinline__ float4 f4z() { return make_float4(0.f, 0.f, 0.f, 0.f); }

// 9-sum sliding window over 3 quads (12 floats), ascending order per output lane
__device__ __forceinline__ float4 slide9q(const float4 a, const float4 b, const float4 c) {
    float f[12] = {a.x, a.y, a.z, a.w, b.x, b.y, b.z, b.w, c.x, c.y, c.z, c.w};
    float s0 = 0.f, s1 = 0.f, s2 = 0.f, s3 = 0.f;
#pragma unroll
    for (int m = 0; m < 9; ++m) {
        s0 += f[m]; s1 += f[m + 1]; s2 += f[m + 2]; s3 += f[m + 3];
    }
    return make_float4(s0, s1, s2, s3);
}

__device__ __forceinline__ void addq(float4& s, const float4 v) {
    s.x += v.x; s.y += v.y; s.z += v.z; s.w += v.w;
}

// decode swizzled block id: bid = tile*16 + seg  =>  XCD = seg % 8 (segment affinity)
__device__ __forceinline__ void decode(int bid, int& b, int& h0, int& w0, int& q0) {
    int k = bid >> 4;          // tile 0..24
    int s = bid & 15;          // segment 0..15
    b = s >> 3;
    h0 = (s & 7) * Hseg;
    w0 = (k / NQT) * Wt;
    q0 = (k % NQT) * Qt;
}

// ---------------- Pass A: fused d+w+h box of t,p -> td = t - mean_t, pd = p - mean_p ----------------
__global__ __launch_bounds__(256) void pa_td(const float4* __restrict__ t,
                                             const float4* __restrict__ p,
                                             float4* __restrict__ TD,
                                             float4* __restrict__ PD) {
    __shared__ float4 sT[WHs * SSTR], sP[WHs * SSTR];   // staged halo slice (quads)
    __shared__ float4 dT[WHs * DSTR], dP[WHs * DSTR];   // d-boxed
    int b, h0, w0, q0;
    decode(blockIdx.x, b, h0, w0, q0);
    int tw = threadIdx.x >> 3, tq = threadIdx.x & 7;
    const float4* tB = t + (size_t)b * FIELD4;
    const float4* pB = p + (size_t)b * FIELD4;
    float4* TDb = TD + (size_t)b * FIELD4;
    float4* PDb = PD + (size_t)b * FIELD4;

    float4 rT[9], rP[9];
#pragma unroll
    for (int m = 0; m < 9; ++m) { rT[m] = f4z(); rP[m] = f4z(); }

    for (int j = h0 - 4; j < h0 + Hseg + 4; ++j) {
        bool jok = (unsigned)j < (unsigned)HH;
        // stage slice j (zero-fill outside volume = exact zero-pad)
        for (int li = threadIdx.x; li < WHs * QHs; li += 256) {
            int lw = li / QHs, lq = li - lw * QHs;
            int gw = w0 - 4 + lw, gq = q0 - 1 + lq;
            float4 vt = f4z(), vp = f4z();
            if (jok && (unsigned)gw < (unsigned)WW && (unsigned)gq < (unsigned)(DD / 4)) {
                int g = j * SLICE4 + gw * (DD / 4) + gq;
                vt = tB[g]; vp = pB[g];
            }
            sT[lw * SSTR + lq] = vt; sP[lw * SSTR + lq] = vp;
        }
        __syncthreads();
        // d-box (ascending d) via register slide
        for (int li = threadIdx.x; li < WHs * Qt; li += 256) {
            int lw = li >> 3, lq = li & 7;
            int o = lw * SSTR + lq;
            dT[lw * DSTR + lq] = slide9q(sT[o], sT[o + 1], sT[o + 2]);
            dP[lw * DSTR + lq] = slide9q(sP[o], sP[o + 1], sP[o + 2]);
        }
        __syncthreads();
        // w-box (ascending w) + ring push
        float4 s1 = f4z(), s2 = f4z();
#pragma unroll
        for (int m = 0; m < 9; ++m) {
            addq(s1, dT[(tw + m) * DSTR + tq]);
            addq(s2, dP[(tw + m) * DSTR + tq]);
        }
#pragma unroll
        for (int m = 0; m < 8; ++m) { rT[m] = rT[m + 1]; rP[m] = rP[m + 1]; }
        rT[8] = s1; rP[8] = s2;
        // h-box (ascending h) -> mean -> td/pd store
        int h = j - 4;
        if (h >= h0) {
            float4 a = f4z(), c = f4z();
#pragma unroll
            for (int m = 0; m < 9; ++m) { addq(a, rT[m]); addq(c, rP[m]); }
            int g = h * SLICE4 + (w0 + tw) * (DD / 4) + (q0 + tq);
            float4 tv = tB[g], pv = pB[g];      // L2-hit: staged 4 steps ago by this segment
            float4 td4, pd4;
            td4.x = tv.x - a.x / WVOL; td4.y = tv.y - a.y / WVOL;
            td4.z = tv.z - a.z / WVOL; td4.w = tv.w - a.w / WVOL;
            pd4.x = pv.x - c.x / WVOL; pd4.y = pv.y - c.y / WVOL;
            pd4.z = pv.z - c.z / WVOL; pd4.w = pv.w - c.w / WVOL;
            TDb[g] = td4; PDb[g] = pd4;
        }
        __syncthreads();
    }
}

// ---------------- Pass B: q=(td^2, pd^2, td*pd) + fused d+w+h box + cc + partial ----------------
__global__ __launch_bounds__(256) void pb_cc(const float4* __restrict__ TD,
                                             const float4* __restrict__ PD,
                                             double* __restrict__ partials) {
    __shared__ float4 sA[WHs * SSTR], sB[WHs * SSTR], sC[WHs * SSTR];
    __shared__ float4 dA[WHs * DSTR], dB[WHs * DSTR], dC[WHs * DSTR];
    int b, h0, w0, q0;
    decode(blockIdx.x, b, h0, w0, q0);
    int tw = threadIdx.x >> 3, tq = threadIdx.x & 7;
    const float4* tdB = TD + (size_t)b * FIELD4;
    const float4* pdB = PD + (size_t)b * FIELD4;

    float4 rA[9], rB[9], rC[9];
#pragma unroll
    for (int m = 0; m < 9; ++m) { rA[m] = f4z(); rB[m] = f4z(); rC[m] = f4z(); }
    double acc = 0.0;

    for (int j = h0 - 4; j < h0 + Hseg + 4; ++j) {
        bool jok = (unsigned)j < (unsigned)HH;
        // stage q on slice j (outside volume: td=pd=0 -> q=0, exact)
        for (int li = threadIdx.x; li < WHs * QHs; li += 256) {
            int lw = li / QHs, lq = li - lw * QHs;
            int gw = w0 - 4 + lw, gq = q0 - 1 + lq;
            float4 qa = f4z(), qb = f4z(), qc = f4z();
            if (jok && (unsigned)gw < (unsigned)WW && (unsigned)gq < (unsigned)(DD / 4)) {
                int g = j * SLICE4 + gw * (DD / 4) + gq;
                float4 td4 = tdB[g], pd4 = pdB[g];
                qa.x = td4.x * td4.x; qa.y = td4.y * td4.y; qa.z = td4.z * td4.z; qa.w = td4.w * td4.w;
                qb.x = pd4.x * pd4.x; qb.y = pd4.y * pd4.y; qb.z = pd4.z * pd4.z; qb.w = pd4.w * pd4.w;
                qc.x = td4.x * pd4.x; qc.y = td4.y * pd4.y; qc.z = td4.z * pd4.z; qc.w = td4.w * pd4.w;
            }
            int o = lw * SSTR + lq;
            sA[o] = qa; sB[o] = qb; sC[o] = qc;
        }
        __syncthreads();
        // d-box (ascending d)
        for (int li = threadIdx.x; li < WHs * Qt; li += 256) {
            int lw = li >> 3, lq = li & 7;
            int o = lw * SSTR + lq, od = lw * DSTR + lq;
            dA[od] = slide9q(sA[o], sA[o + 1], sA[o + 2]);
            dB[od] = slide9q(sB[o], sB[o + 1], sB[o + 2]);
            dC[od] = slide9q(sC[o], sC[o + 1], sC[o + 2]);
        }
        __syncthreads();
        // w-box (ascending w) + ring push
        float4 s1 = f4z(), s2 = f4z(), s3 = f4z();
#pragma unroll
        for (int m = 0; m < 9; ++m) {
            int o = (tw + m) * DSTR + tq;
            addq(s1, dA[o]); addq(s2, dB[o]); addq(s3, dC[o]);
        }
#pragma unroll
        for (int m = 0; m < 8; ++m) { rA[m] = rA[m + 1]; rB[m] = rB[m + 1]; rC[m] = rC[m + 1]; }
        rA[8] = s1; rB[8] = s2; rC[8] = s3;
        // h-box (ascending h) + cc + accumulate
        int h = j - 4;
        if (h >= h0) {
            float4 sa = f4z(), sb = f4z(), sc = f4z();
#pragma unroll
            for (int m = 0; m < 9; ++m) { addq(sa, rA[m]); addq(sb, rB[m]); addq(sc, rC[m]); }
            float c0 = sc.x / sqrtf((sa.x + EPSF) * (sb.x + EPSF));
            float c1 = sc.y / sqrtf((sa.y + EPSF) * (sb.y + EPSF));
            float c2 = sc.z / sqrtf((sa.z + EPSF) * (sb.z + EPSF));
            float c3 = sc.w / sqrtf((sa.w + EPSF) * (sb.w + EPSF));
            acc += (double)c0 + (double)c1 + (double)c2 + (double)c3;
        }
        __syncthreads();
    }

    // block reduce
#pragma unroll
    for (int off = 32; off > 0; off >>= 1)
        acc += __shfl_down(acc, off, 64);
    __shared__ double red[4];
    int lane = threadIdx.x & 63;
    int wv = threadIdx.x >> 6;
    if (lane == 0) red[wv] = acc;
    __syncthreads();
    if (threadIdx.x == 0)
        partials[blockIdx.x] = red[0] + red[1] + red[2] + red[3];
}

// ---------------- K7: reduce 400 partials + finalize ----------------
__global__ void k7_reduce(const double* __restrict__ partials, float* __restrict__ out) {
    __shared__ double red[256];
    double s = 0.0;
    for (int i = threadIdx.x; i < NBLK; i += 256)
        s += partials[i];
    red[threadIdx.x] = s;
    __syncthreads();
    for (int ofs = 128; ofs > 0; ofs >>= 1) {
        if (threadIdx.x < ofs) red[threadIdx.x] += red[threadIdx.x + ofs];
        __syncthreads();
    }
    if (threadIdx.x == 0)
        out[0] = -(float)(red[0] / (double)NV);
}

} // anonymous namespace

extern "C" void kernel_launch(void* const* d_in, const int* in_sizes, int n_in,
                              void* d_out, int out_size, void* d_ws, size_t ws_size,
                              hipStream_t stream) {
    const float4* t = (const float4*)d_in[0];
    const float4* p = (const float4*)d_in[1];
    float* out = (float*)d_out;

    char* ws = (char*)d_ws;
    double* partials = (double*)ws;                    // 400 doubles
    float4* TD = (float4*)(ws + 16384);                // NV floats (as quads)
    float4* PD = TD + (NV / 4);                        // NV floats

    // Pass A: td/pd fields (mean subtracted)
    pa_td<<<NBLK, 256, 0, stream>>>(t, p, TD, PD);
    // Pass B: cc partials
    pb_cc<<<NBLK, 256, 0, stream>>>(TD, PD, partials);
    // Final reduce
    k7_reduce<<<1, 256, 0, stream>>>(partials, out);
}